// Round 4
// baseline (634.017 us; speedup 1.0000x reference)
//
#include <hip/hip_runtime.h>
#include <hip/hip_bf16.h>
#include <stdint.h>

// Problem constants (match reference)
#define BN   4096
#define SN   200
#define EN   128
#define HN   128      // ATT_H
#define RPB  8        // rows (batch entries) per persistent block
#define NBLK (BN / RPB)   // 512 blocks, 1 resident per CU (102.4KB dbuf LDS)

typedef __attribute__((ext_vector_type(8)))  short  short8;
typedef __attribute__((ext_vector_type(16))) float  floatx16;

// Raw barrier with LDS-only drain: keeps global loads (vmcnt) IN FLIGHT
// across the barrier, unlike __syncthreads() which drains vmcnt(0).
#define SYNC_LGK() do {                                            \
    asm volatile("s_waitcnt lgkmcnt(0)\n\ts_barrier" ::: "memory");\
    __builtin_amdgcn_sched_barrier(0);                             \
  } while (0)
#define ASM_VMCNT0() do {                                          \
    asm volatile("s_waitcnt vmcnt(0)" ::: "memory");               \
    __builtin_amdgcn_sched_barrier(0);                             \
  } while (0)

__device__ __forceinline__ unsigned short f2bf(float f) {
  union { float f; uint32_t u; } c; c.f = f;
  uint32_t r = c.u + 0x7fffu + ((c.u >> 16) & 1u);   // RNE
  return (unsigned short)(r >> 16);
}
__device__ __forceinline__ float bf2f(unsigned short h) {
  union { uint32_t u; float f; } c; c.u = ((uint32_t)h) << 16;
  return c.f;
}
__device__ __forceinline__ uint32_t pk2(float x, float y) {
#if defined(__has_builtin) && __has_builtin(__builtin_amdgcn_cvt_pk_bf16_f32)
  typedef __bf16 bf16x2 __attribute__((ext_vector_type(2)));
  return __builtin_bit_cast(uint32_t, __builtin_amdgcn_cvt_pk_bf16_f32(x, y));
#else
  return (uint32_t)f2bf(x) | ((uint32_t)f2bf(y) << 16);
#endif
}
__device__ __forceinline__ float bcast_lane(float v, int l) {
  return __builtin_bit_cast(float, __builtin_amdgcn_readlane(__builtin_bit_cast(int, v), l));
}

// LDS byte offset of 16B chunk g (g = e>>3) of row s, XOR-16 swizzled.
__device__ __forceinline__ int aoff(int s, int g) {
  return s * 256 + (((g ^ (s & 15)) << 4));
}

// Issue one behavior row (200x128 f32 = 6400 float4) across 512 threads.
__device__ __forceinline__ void issue_row(const float* __restrict__ src, int tid,
                                          float4 (&va)[13]) {
  #pragma unroll
  for (int u = 0; u < 12; ++u) {
    int q = u * 512 + tid;                       // q < 6144 always
    va[u] = *(const float4*)(src + (q >> 5) * EN + ((q & 31) << 2));
  }
  if (tid < 256) {                               // tail: q = 6144..6399
    int q = 6144 + tid;
    va[12] = *(const float4*)(src + (q >> 5) * EN + ((q & 31) << 2));
  }
}

// Convert held row to bf16 into swizzled LDS buffer.
__device__ __forceinline__ void convert_row(unsigned short* dst, int tid,
                                            const float4 (&va)[13]) {
  #pragma unroll
  for (int u = 0; u < 12; ++u) {
    int q = u * 512 + tid, s = q >> 5, e4 = (q & 31) << 2;
    uint2 pk = make_uint2(pk2(va[u].x, va[u].y), pk2(va[u].z, va[u].w));
    *(uint2*)((char*)dst + s * 256 + ((((e4 >> 3) ^ (s & 15))) << 4) + ((e4 & 7) << 1)) = pk;
  }
  if (tid < 256) {
    int q = 6144 + tid, s = q >> 5, e4 = (q & 31) << 2;
    uint2 pk = make_uint2(pk2(va[12].x, va[12].y), pk2(va[12].z, va[12].w));
    *(uint2*)((char*)dst + s * 256 + ((((e4 >> 3) ^ (s & 15))) << 4) + ((e4 & 7) << 1)) = pk;
  }
}

// ---------------------------------------------------------------------------
// Prep: repack W_b^T into bf16 MFMA A-fragment layout, once.
// ---------------------------------------------------------------------------
__global__ void din_prep(const float* __restrict__ fc1w, short8* __restrict__ ws_afr) {
  const int t    = blockIdx.x & 7;
  const int wv   = blockIdx.x >> 3;
  const int lane = threadIdx.x;      // 0..63
  const int half = lane >> 5;
  const int hcol = wv * 32 + (lane & 31);
  short8 fr;
  #pragma unroll
  for (int j = 0; j < 8; ++j) {
    int e = t * 16 + half * 8 + j;
    fr[j] = (short)f2bf(fc1w[e * HN + hcol]);
  }
  ws_afr[((wv * 8 + t) << 6) + lane] = fr;
}

// ---------------------------------------------------------------------------
// Kernel A: persistent 8-wave block, 1 per CU, LDS double-buffered rows.
// Loads for row k+1 issued at top of iteration k and kept IN FLIGHT across
// all phase barriers (raw s_barrier + lgkmcnt-only waits); drained by a
// single explicit vmcnt(0) right before the bf16 convert at iteration end.
// ---------------------------------------------------------------------------
__global__ __launch_bounds__(512, 2)
void din_attn(const float* __restrict__ behavior, const float* __restrict__ cand,
              const float* __restrict__ fc1w, const float* __restrict__ fc1b,
              const float* __restrict__ fc2w, const short8* __restrict__ ws_afr,
              float* __restrict__ ws_ui) {
  __shared__ unsigned short Abuf[2][SN * EN];   // 2 x 51200 B bf16 (swizzled)
  __shared__ float scores_s[SN];                //   800 B
  __shared__ float cvec_all[RPB][HN];           //  4096 B (cvec for all 8 rows)
  __shared__ float cand_all[RPB][EN];           //  4096 B
  __shared__ float ui_s[EN];                    //   512 B   -> ~111.9 KB total

  const int tid  = threadIdx.x;
  const int wv   = tid >> 6;                    // 0..7
  const int lane = tid & 63;
  const int half = lane >> 5;
  const int l31  = lane & 31;
  const int ht   = wv & 3;                      // h-tile (0..3)
  const int stb  = (wv >> 2) ? 4 : 0;           // s-tile split: waves 0-3 do
  const int ste  = (wv >> 2) ? 7 : 4;           // st 0..3, waves 4-7 do st 4..6

  const int base = blockIdx.x * RPB;

  // ---- prologue (plain __syncthreads is fine here; one-time) ----
  if (tid < SN) scores_s[tid] = 0.f;
  if (tid < EN) ui_s[tid] = 0.f;
  if (tid < RPB * EN / 4)                       // 256 threads: 8 cand rows
    ((float4*)cand_all)[tid] = ((const float4*)(cand + (size_t)base * EN))[tid];

  // A-fragments (L2-hot b128) + fc2 weights
  short8 afr[8];
  #pragma unroll
  for (int t = 0; t < 8; ++t) afr[t] = ws_afr[((ht * 8 + t) << 6) + lane];
  float wmul[16];
  #pragma unroll
  for (int i = 0; i < 16; ++i) {
    int hr = ht * 32 + (i & 3) + ((i >> 2) << 3) + (half << 2);
    wmul[i] = fc2w[hr];
  }
  __syncthreads();                              // cand_all ready

  // issue behavior row 'base' -> regs (102KB in flight)
  float4 va[13];
  issue_row(behavior + (size_t)base * SN * EN, tid, va);

  // cvec for ALL 8 rows under the HBM shadow:
  // cvec_all[r][h] = fc1b[h] + sum_e cand[r][e] * W_c[e][h]
  {
    const int h  = tid & 127;
    const int r0 = tid >> 7;                    // 0..3 -> rows r0, r0+4
    float a0 = fc1b[h], a1 = a0;
    const float* wc = fc1w + (size_t)EN * HN + h;
    #pragma unroll 8
    for (int e = 0; e < EN; ++e) {
      float w = wc[(size_t)e * HN];             // coalesced across h
      a0 = fmaf(cand_all[r0][e],     w, a0);
      a1 = fmaf(cand_all[r0 + 4][e], w, a1);
    }
    cvec_all[r0][h]     = a0;
    cvec_all[r0 + 4][h] = a1;
  }

  convert_row(Abuf[0], tid, va);                // compiler waits vmcnt here
  __syncthreads();

  // ---- main loop over 8 rows ----
  for (int it = 0; it < RPB; ++it) {
    const int cur = it & 1;

    // A: issue next row's loads; sched_barrier pins them HERE so the
    // scheduler cannot sink them down to the convert (they stay in
    // flight across B/C/D thanks to the lgkmcnt-only barriers).
    if (it + 1 < RPB) {
      issue_row(behavior + (size_t)(base + it + 1) * SN * EN, tid, va);
      __builtin_amdgcn_sched_barrier(0);
    }

    // B: scores via MFMA (C cols = s; h-reduction in-lane)
    float cadd[16];
    #pragma unroll
    for (int i = 0; i < 16; ++i) {
      int hr = ht * 32 + (i & 3) + ((i >> 2) << 3) + (half << 2);
      cadd[i] = cvec_all[it][hr];
    }
    for (int st = stb; st < ste; ++st) {
      floatx16 acc;
      #pragma unroll
      for (int i = 0; i < 16; ++i) acc[i] = cadd[i];
      const int srow = st * 32 + l31;
      const int sr   = (srow < SN) ? srow : (SN - 1);
      #pragma unroll
      for (int t = 0; t < 8; ++t) {
        const short8 bfr = *(const short8*)((const char*)Abuf[cur] + aoff(sr, 2 * t + half));
        acc = __builtin_amdgcn_mfma_f32_32x32x16_bf16(afr[t], bfr, acc, 0, 0, 0);
      }
      float part = 0.f;
      #pragma unroll
      for (int i = 0; i < 16; ++i)
        part = fmaf(fmaxf(acc[i], 0.f), wmul[i], part);
      part += __shfl_xor(part, 32, 64);
      if (lane < 32 && srow < SN) atomicAdd(&scores_s[srow], part);
    }
    SYNC_LGK();                                  // scores visible; vmcnt live

    // C: softmax in place (wave 0)
    if (wv == 0) {
      float v0[4];
      #pragma unroll
      for (int k = 0; k < 4; ++k) {
        int s = k * 64 + lane;
        v0[k] = (s < SN) ? scores_s[s] : -3.0e38f;
      }
      float m = fmaxf(fmaxf(v0[0], v0[1]), fmaxf(v0[2], v0[3]));
      #pragma unroll
      for (int off = 32; off >= 1; off >>= 1) m = fmaxf(m, __shfl_xor(m, off, 64));
      float e0[4], sum = 0.f;
      #pragma unroll
      for (int k = 0; k < 4; ++k) { e0[k] = __expf(v0[k] - m); sum += e0[k]; }
      #pragma unroll
      for (int off = 32; off >= 1; off >>= 1) sum += __shfl_xor(sum, off, 64);
      float inv = 1.0f / sum;
      #pragma unroll
      for (int k = 0; k < 4; ++k) {
        int s = k * 64 + lane;
        if (s < SN) scores_s[s] = e0[k] * inv;   // attn in place
      }
    }
    SYNC_LGK();                                  // attn visible; vmcnt live

    // D: ui[e] = sum_s attn[s]*beh[s][e]
    {
      const int g  = tid & 15;
      const int sg = tid >> 4;                   // 0..31
      float ua[8] = {0.f,0.f,0.f,0.f,0.f,0.f,0.f,0.f};
      for (int s = sg; s < SN; s += 32) {
        float a = scores_s[s];
        const short8 bv = *(const short8*)((const char*)Abuf[cur] + aoff(s, g));
        #pragma unroll
        for (int j = 0; j < 8; ++j) ua[j] = fmaf(a, bf2f((unsigned short)bv[j]), ua[j]);
      }
      #pragma unroll
      for (int j = 0; j < 8; ++j) {
        ua[j] += __shfl_xor(ua[j], 16, 64);
        ua[j] += __shfl_xor(ua[j], 32, 64);
      }
      if (lane < 16) {
        #pragma unroll
        for (int j = 0; j < 8; ++j) atomicAdd(&ui_s[(g << 3) + j], ua[j]);
      }
    }
    SYNC_LGK();                                  // ui_s visible; vmcnt live

    // write ui row + reset accumulators for next row (disjoint thread ranges)
    if (tid < EN) {
      ws_ui[(size_t)(base + it) * EN + tid] = ui_s[tid];
      ui_s[tid] = 0.f;
    } else if (tid >= 256 && tid < 256 + SN) {
      scores_s[tid - 256] = 0.f;
    }

    // E: drain the prefetched loads ONLY here, then convert into other buffer
    if (it + 1 < RPB) {
      ASM_VMCNT0();
      convert_row(Abuf[cur ^ 1], tid, va);
    }
    SYNC_LGK();                                  // converted buf + resets visible
  }
}

// ---------------------------------------------------------------------------
// Kernel B: MLP head. Block = 4 batch rows (1024 blocks, 4/CU).
// ---------------------------------------------------------------------------
__global__ __launch_bounds__(256, 4)
void din_mlp(const float* __restrict__ ws_ui, const float* __restrict__ cand,
             const float* __restrict__ w1, const float* __restrict__ b1,
             const float* __restrict__ w2, const float* __restrict__ b2,
             float* __restrict__ out) {
  const int tid  = threadIdx.x;
  const int lane = tid & 63;
  const int wv   = tid >> 6;
  const int r0   = blockIdx.x * 4;

  float xr[4][4];
  #pragma unroll
  for (int r = 0; r < 4; ++r) {
    #pragma unroll
    for (int c = 0; c < 4; ++c) {
      int i = c * 64 + lane;
      int row = r0 + r;
      xr[r][c] = (i < 128) ? ws_ui[row * 128 + i] : cand[row * 128 + (i - 128)];
    }
  }

  const int j = tid;
  const float bj = b1[j];
  float acc[4] = {bj, bj, bj, bj};

  #pragma unroll
  for (int c = 0; c < 4; ++c) {
    #pragma unroll 8
    for (int il = 0; il < 64; ++il) {
      float w = w1[(c * 64 + il) * 256 + j];
      #pragma unroll
      for (int r = 0; r < 4; ++r)
        acc[r] = fmaf(bcast_lane(xr[r][c], il), w, acc[r]);
    }
  }

  const float w2j = w2[j];
  float part[4];
  #pragma unroll
  for (int r = 0; r < 4; ++r) part[r] = fmaxf(acc[r], 0.f) * w2j;
  #pragma unroll
  for (int off = 32; off >= 1; off >>= 1) {
    #pragma unroll
    for (int r = 0; r < 4; ++r) part[r] += __shfl_xor(part[r], off, 64);
  }

  __shared__ float red[4][4];
  if (lane == 0) {
    #pragma unroll
    for (int r = 0; r < 4; ++r) red[wv][r] = part[r];
  }
  __syncthreads();
  if (tid < 4)
    out[r0 + tid] = red[0][tid] + red[1][tid] + red[2][tid] + red[3][tid] + b2[0];
}

extern "C" void kernel_launch(void* const* d_in, const int* in_sizes, int n_in,
                              void* d_out, int out_size, void* d_ws, size_t ws_size,
                              hipStream_t stream) {
  const float* behavior = (const float*)d_in[0];
  const float* cand     = (const float*)d_in[1];
  const float* fc1w     = (const float*)d_in[2];
  const float* fc1b     = (const float*)d_in[3];
  const float* fc2w     = (const float*)d_in[4];
  // d_in[5] = fc2_b: constant shift before softmax -> softmax-invariant, skipped
  const float* m1w      = (const float*)d_in[6];
  const float* m1b      = (const float*)d_in[7];
  const float* m2w      = (const float*)d_in[8];
  const float* m2b      = (const float*)d_in[9];
  float* outp    = (float*)d_out;
  float* ws_ui   = (float*)d_ws;                                   // 2 MB
  short8* ws_afr = (short8*)((char*)d_ws + (size_t)BN * EN * 4);   // 32 KB

  din_prep<<<32, 64, 0, stream>>>(fc1w, ws_afr);
  din_attn<<<NBLK, 512, 0, stream>>>(behavior, cand, fc1w, fc1b, fc2w, ws_afr, ws_ui);
  din_mlp<<<BN / 4, 256, 0, stream>>>(ws_ui, cand, m1w, m1b, m2w, m2b, outp);
}

// Round 7
// 616.019 us; speedup vs baseline: 1.0292x; 1.0292x over previous
//
#include <hip/hip_runtime.h>
#include <hip/hip_bf16.h>
#include <stdint.h>

// Problem constants (match reference)
#define BN   4096
#define SN   200
#define EN   128
#define HN   128      // ATT_H
#define MHN  256      // MLP_H
#define RPB  16       // rows (batch entries) per persistent block
#define NBLK (BN / RPB)   // 256 blocks = one per CU (128KB LDS, 8 waves)

typedef __attribute__((ext_vector_type(8)))  short  short8;
typedef __attribute__((ext_vector_type(16))) float  floatx16;

// Raw barrier with LDS-only drain: keeps global loads (vmcnt) IN FLIGHT
// across the barrier, unlike __syncthreads() which drains vmcnt(0).
#define SYNC_LGK() do {                                            \
    asm volatile("s_waitcnt lgkmcnt(0)\n\ts_barrier" ::: "memory");\
    __builtin_amdgcn_sched_barrier(0);                             \
  } while (0)
#define ASM_VMCNT0() do {                                          \
    asm volatile("s_waitcnt vmcnt(0)" ::: "memory");               \
    __builtin_amdgcn_sched_barrier(0);                             \
  } while (0)

__device__ __forceinline__ unsigned short f2bf(float f) {
  union { float f; uint32_t u; } c; c.f = f;
  uint32_t r = c.u + 0x7fffu + ((c.u >> 16) & 1u);   // RNE
  return (unsigned short)(r >> 16);
}
__device__ __forceinline__ float bf2f(unsigned short h) {
  union { uint32_t u; float f; } c; c.u = ((uint32_t)h) << 16;
  return c.f;
}
__device__ __forceinline__ uint32_t pk2(float x, float y) {
#if defined(__has_builtin) && __has_builtin(__builtin_amdgcn_cvt_pk_bf16_f32)
  typedef __bf16 bf16x2 __attribute__((ext_vector_type(2)));
  return __builtin_bit_cast(uint32_t, __builtin_amdgcn_cvt_pk_bf16_f32(x, y));
#else
  return (uint32_t)f2bf(x) | ((uint32_t)f2bf(y) << 16);
#endif
}

// LDS byte offset of 16B chunk g (g = e>>3) of row s, XOR-16 swizzled.
__device__ __forceinline__ int aoff(int s, int g) {
  return s * 256 + (((g ^ (s & 15)) << 4));
}

// Issue one behavior row (200x128 f32 = 6400 float4) across 512 threads.
__device__ __forceinline__ void issue_row(const float* __restrict__ src, int tid,
                                          float4 (&va)[13]) {
  #pragma unroll
  for (int u = 0; u < 12; ++u) {
    int q = u * 512 + tid;                       // q < 6144 always
    va[u] = *(const float4*)(src + (q >> 5) * EN + ((q & 31) << 2));
  }
  if (tid < 256) {                               // tail: q = 6144..6399
    int q = 6144 + tid;
    va[12] = *(const float4*)(src + (q >> 5) * EN + ((q & 31) << 2));
  }
}

// Convert held row to bf16 into swizzled LDS buffer.
__device__ __forceinline__ void convert_row(unsigned short* dst, int tid,
                                            const float4 (&va)[13]) {
  #pragma unroll
  for (int u = 0; u < 12; ++u) {
    int q = u * 512 + tid, s = q >> 5, e4 = (q & 31) << 2;
    uint2 pk = make_uint2(pk2(va[u].x, va[u].y), pk2(va[u].z, va[u].w));
    *(uint2*)((char*)dst + s * 256 + ((((e4 >> 3) ^ (s & 15))) << 4) + ((e4 & 7) << 1)) = pk;
  }
  if (tid < 256) {
    int q = 6144 + tid, s = q >> 5, e4 = (q & 31) << 2;
    uint2 pk = make_uint2(pk2(va[12].x, va[12].y), pk2(va[12].z, va[12].w));
    *(uint2*)((char*)dst + s * 256 + ((((e4 >> 3) ^ (s & 15))) << 4) + ((e4 & 7) << 1)) = pk;
  }
}

// ---------------------------------------------------------------------------
// Single fused kernel: persistent 8-wave block, one per CU, 16 rows each.
// Per row: MFMA scores -> softmax -> ui (all in LDS), with next row's 102KB
// HBM stream in flight across lgkmcnt-only barriers (T4 discipline).
// Epilogue: MLP head for the block's 16 rows straight from LDS.
// ---------------------------------------------------------------------------
__global__ __launch_bounds__(512, 2)
void din_fused(const float* __restrict__ behavior, const float* __restrict__ cand,
               const float* __restrict__ fc1w, const float* __restrict__ fc1b,
               const float* __restrict__ fc2w,
               const float* __restrict__ m1w, const float* __restrict__ m1b,
               const float* __restrict__ m2w, const float* __restrict__ m2b,
               float* __restrict__ out) {
  __shared__ unsigned short Abuf[2][SN * EN];   // 2 x 51200 B bf16 (swizzled)
  __shared__ float scores_s[SN];                //    800 B
  __shared__ float cvec_all[RPB][HN];           //   8192 B
  __shared__ float cand_all[RPB][EN];           //   8192 B
  __shared__ float ui_all[RPB][EN];             //   8192 B
  __shared__ float red8[8][8];                  //    256 B  -> ~128.1 KB total

  const int tid  = threadIdx.x;
  const int wv   = tid >> 6;                    // 0..7
  const int lane = tid & 63;
  const int half = lane >> 5;
  const int l31  = lane & 31;
  const int ht   = wv & 3;                      // h-tile (0..3)
  const int stb  = (wv >> 2) ? 4 : 0;           // s-tile split: waves 0-3 do
  const int ste  = (wv >> 2) ? 7 : 4;           // st 0..3, waves 4-7 do st 4..6

  const int base = blockIdx.x * RPB;

  // ---- prologue (one-time; plain __syncthreads fine) ----
  if (tid < SN) scores_s[tid] = 0.f;
  #pragma unroll
  for (int i = tid; i < RPB * EN; i += 512) ((float*)ui_all)[i] = 0.f;
  // 512 float4 = 16 cand rows, one per thread
  ((float4*)cand_all)[tid] = ((const float4*)(cand + (size_t)base * EN))[tid];
  __syncthreads();                              // cand_all ready

  // issue behavior row 'base' -> regs (102KB in flight)
  float4 va[13];
  issue_row(behavior + (size_t)base * SN * EN, tid, va);

  // A-fragments: inline W_b^T repack (was din_prep), L2-hot, under HBM shadow.
  // afr[t][j] = bf16(fc1w[(t*16 + half*8 + j)*HN + ht*32 + l31])
  short8 afr[8];
  #pragma unroll
  for (int t = 0; t < 8; ++t) {
    #pragma unroll
    for (int j = 0; j < 8; ++j) {
      int e = t * 16 + half * 8 + j;
      afr[t][j] = (short)f2bf(fc1w[e * HN + ht * 32 + l31]);
    }
  }
  float wmul[16];
  #pragma unroll
  for (int i = 0; i < 16; ++i) {
    int hr = ht * 32 + (i & 3) + ((i >> 2) << 3) + (half << 2);
    wmul[i] = fc2w[hr];
  }

  // cvec for ALL 16 rows under the HBM shadow:
  // cvec_all[r][h] = fc1b[h] + sum_e cand[r][e] * W_c[e][h]
  {
    const int h  = tid & 127;
    const int r0 = tid >> 7;                    // 0..3 -> rows r0, r0+4, r0+8, r0+12
    float a0 = fc1b[h], a1 = a0, a2 = a0, a3 = a0;
    const float* wc = fc1w + (size_t)EN * HN + h;
    #pragma unroll 8
    for (int e = 0; e < EN; ++e) {
      float w = wc[(size_t)e * HN];             // coalesced across h
      a0 = fmaf(cand_all[r0][e],      w, a0);
      a1 = fmaf(cand_all[r0 + 4][e],  w, a1);
      a2 = fmaf(cand_all[r0 + 8][e],  w, a2);
      a3 = fmaf(cand_all[r0 + 12][e], w, a3);
    }
    cvec_all[r0][h]      = a0;
    cvec_all[r0 + 4][h]  = a1;
    cvec_all[r0 + 8][h]  = a2;
    cvec_all[r0 + 12][h] = a3;
  }

  convert_row(Abuf[0], tid, va);                // compiler waits vmcnt here
  __syncthreads();                              // Abuf0 + cvec_all + ui_all ready

  // ---- main loop over 16 rows (verified structure, unchanged) ----
  for (int it = 0; it < RPB; ++it) {
    const int cur = it & 1;

    // A: issue next row's loads; pinned here, in flight across B/C/D.
    if (it + 1 < RPB) {
      issue_row(behavior + (size_t)(base + it + 1) * SN * EN, tid, va);
      __builtin_amdgcn_sched_barrier(0);
    }

    // B: scores via MFMA (C cols = s; h-reduction in-lane)
    float cadd[16];
    #pragma unroll
    for (int i = 0; i < 16; ++i) {
      int hr = ht * 32 + (i & 3) + ((i >> 2) << 3) + (half << 2);
      cadd[i] = cvec_all[it][hr];
    }
    for (int st = stb; st < ste; ++st) {
      floatx16 acc;
      #pragma unroll
      for (int i = 0; i < 16; ++i) acc[i] = cadd[i];
      const int srow = st * 32 + l31;
      const int sr   = (srow < SN) ? srow : (SN - 1);
      #pragma unroll
      for (int t = 0; t < 8; ++t) {
        const short8 bfr = *(const short8*)((const char*)Abuf[cur] + aoff(sr, 2 * t + half));
        acc = __builtin_amdgcn_mfma_f32_32x32x16_bf16(afr[t], bfr, acc, 0, 0, 0);
      }
      float part = 0.f;
      #pragma unroll
      for (int i = 0; i < 16; ++i)
        part = fmaf(fmaxf(acc[i], 0.f), wmul[i], part);
      part += __shfl_xor(part, 32, 64);
      if (lane < 32 && srow < SN) atomicAdd(&scores_s[srow], part);
    }
    SYNC_LGK();                                  // scores visible; vmcnt live

    // C: softmax in place (wave 0)
    if (wv == 0) {
      float v0[4];
      #pragma unroll
      for (int k = 0; k < 4; ++k) {
        int s = k * 64 + lane;
        v0[k] = (s < SN) ? scores_s[s] : -3.0e38f;
      }
      float m = fmaxf(fmaxf(v0[0], v0[1]), fmaxf(v0[2], v0[3]));
      #pragma unroll
      for (int off = 32; off >= 1; off >>= 1) m = fmaxf(m, __shfl_xor(m, off, 64));
      float e0[4], sum = 0.f;
      #pragma unroll
      for (int k = 0; k < 4; ++k) { e0[k] = __expf(v0[k] - m); sum += e0[k]; }
      #pragma unroll
      for (int off = 32; off >= 1; off >>= 1) sum += __shfl_xor(sum, off, 64);
      float inv = 1.0f / sum;
      #pragma unroll
      for (int k = 0; k < 4; ++k) {
        int s = k * 64 + lane;
        if (s < SN) scores_s[s] = e0[k] * inv;   // attn in place
      }
    }
    SYNC_LGK();                                  // attn visible; vmcnt live

    // D: ui_all[it][e] = sum_s attn[s]*beh[s][e]
    {
      const int g  = tid & 15;
      const int sg = tid >> 4;                   // 0..31
      float ua[8] = {0.f,0.f,0.f,0.f,0.f,0.f,0.f,0.f};
      for (int s = sg; s < SN; s += 32) {
        float a = scores_s[s];
        const short8 bv = *(const short8*)((const char*)Abuf[cur] + aoff(s, g));
        #pragma unroll
        for (int j = 0; j < 8; ++j) ua[j] = fmaf(a, bf2f((unsigned short)bv[j]), ua[j]);
      }
      #pragma unroll
      for (int j = 0; j < 8; ++j) {
        ua[j] += __shfl_xor(ua[j], 16, 64);
        ua[j] += __shfl_xor(ua[j], 32, 64);
      }
      if (lane < 16) {
        #pragma unroll
        for (int j = 0; j < 8; ++j) atomicAdd(&ui_all[it][(g << 3) + j], ua[j]);
      }
    }
    SYNC_LGK();                                  // ui_all[it] complete; vmcnt live

    // reset scores for next row
    if (tid < SN) scores_s[tid] = 0.f;

    // E: drain the prefetched loads ONLY here, then convert into other buffer
    if (it + 1 < RPB) {
      ASM_VMCNT0();
      convert_row(Abuf[cur ^ 1], tid, va);
    }
    SYNC_LGK();                                  // converted buf + reset visible
  }

  // ---- fused MLP epilogue: logits for the block's 16 rows, x straight
  // from LDS (ui_all / cand_all). Thread = mlp hidden col j for 8 rows. ----
  {
    const int j  = tid & 255;                    // 0..255
    const int rh = tid >> 8;                     // 0: rows 0-7, 1: rows 8-15
    const float bj = m1b[j];
    float accm[8];
    #pragma unroll
    for (int r = 0; r < 8; ++r) accm[r] = bj;
    #pragma unroll 4
    for (int i = 0; i < 128; ++i) {
      float w = m1w[i * MHN + j];                // coalesced across j
      #pragma unroll
      for (int r = 0; r < 8; ++r)
        accm[r] = fmaf(ui_all[rh * 8 + r][i], w, accm[r]);   // LDS broadcast
    }
    #pragma unroll 4
    for (int i = 0; i < 128; ++i) {
      float w = m1w[(128 + i) * MHN + j];
      #pragma unroll
      for (int r = 0; r < 8; ++r)
        accm[r] = fmaf(cand_all[rh * 8 + r][i], w, accm[r]);
    }
    const float w2j = m2w[j];
    float prt[8];
    #pragma unroll
    for (int r = 0; r < 8; ++r) prt[r] = fmaxf(accm[r], 0.f) * w2j;
    #pragma unroll
    for (int off = 32; off >= 1; off >>= 1) {
      #pragma unroll
      for (int r = 0; r < 8; ++r) prt[r] += __shfl_xor(prt[r], off, 64);
    }
    if (lane == 0) {
      #pragma unroll
      for (int r = 0; r < 8; ++r) red8[wv][r] = prt[r];      // wave wv: rh=wv>>2
    }
  }
  __syncthreads();
  if (tid < RPB) {
    const int g = tid >> 3, rr = tid & 7;        // row group, local row
    float s = red8[g * 4 + 0][rr] + red8[g * 4 + 1][rr]
            + red8[g * 4 + 2][rr] + red8[g * 4 + 3][rr];
    out[base + tid] = s + m2b[0];
  }
}

extern "C" void kernel_launch(void* const* d_in, const int* in_sizes, int n_in,
                              void* d_out, int out_size, void* d_ws, size_t ws_size,
                              hipStream_t stream) {
  const float* behavior = (const float*)d_in[0];
  const float* cand     = (const float*)d_in[1];
  const float* fc1w     = (const float*)d_in[2];
  const float* fc1b     = (const float*)d_in[3];
  const float* fc2w     = (const float*)d_in[4];
  // d_in[5] = fc2_b: constant shift before softmax -> softmax-invariant, skipped
  const float* m1w      = (const float*)d_in[6];
  const float* m1b      = (const float*)d_in[7];
  const float* m2w      = (const float*)d_in[8];
  const float* m2b      = (const float*)d_in[9];
  float* outp    = (float*)d_out;

  din_fused<<<NBLK, 512, 0, stream>>>(behavior, cand, fc1w, fc1b, fc2w,
                                      m1w, m1b, m2w, m2b, outp);
}